// Round 6
// baseline (39378.641 us; speedup 1.0000x reference)
//
#include <hip/hip_runtime.h>
#include <hip/hip_bf16.h>

#define BB 256
#define TT 2000
#define FF 42
#define NTHREADS 896

__device__ __forceinline__ float bf2f(__hip_bfloat16 v) { return __bfloat162float(v); }
__device__ __forceinline__ float sig(float x) { return 1.0f / (1.0f + __expf(-x)); }
__device__ __forceinline__ float tanh_fast(float x) {
    float e = __expf(2.0f * x);
    return 1.0f - 2.0f / (e + 1.0f);
}
__device__ __forceinline__ float unpk_lo(unsigned u) {
    union { unsigned u; float f; } c; c.u = u << 16; return c.f;
}
__device__ __forceinline__ float unpk_hi(unsigned u) {
    union { unsigned u; float f; } c; c.u = u & 0xffff0000u; return c.f;
}
// fp32 -> bf16 bits, round-to-nearest-even
__device__ __forceinline__ unsigned f2bfbits(float f) {
    union { float f; unsigned u; } c; c.f = f;
    unsigned r = c.u + 0x7FFFu + ((c.u >> 16) & 1u);
    return r >> 16;
}
__device__ __forceinline__ unsigned pack2(float a, float b) {
    return f2bfbits(a) | (f2bfbits(b) << 16);
}
__device__ __forceinline__ float gld(const void* p, int i, bool f32) {
    return f32 ? ((const float*)p)[i] : bf2f(((const __hip_bfloat16*)p)[i]);
}

// LDS weight row (uint4 = 8 packed bf16 per read) · fp32 input (LDS float4
// broadcast), 4 acc chains. ONLY run on threads that hold NO register weight
// array (round-5 lesson: running this on wden-holders => per-step spills).
template<int NQ>
__device__ __forceinline__ float dotL(const unsigned* __restrict__ wrow,
                                      const float4* __restrict__ in, float acc) {
    const uint4* w4 = (const uint4*)wrow;
    float a0 = acc, a1 = 0.f, a2 = 0.f, a3 = 0.f;
    #pragma unroll
    for (int q = 0; q < NQ; ++q) {
        uint4 u = w4[q];
        float4 d0 = in[2 * q], d1 = in[2 * q + 1];
        a0 = fmaf(unpk_lo(u.x), d0.x, a0);
        a1 = fmaf(unpk_hi(u.x), d0.y, a1);
        a2 = fmaf(unpk_lo(u.y), d0.z, a2);
        a3 = fmaf(unpk_hi(u.y), d0.w, a3);
        a0 = fmaf(unpk_lo(u.z), d1.x, a0);
        a1 = fmaf(unpk_hi(u.z), d1.y, a1);
        a2 = fmaf(unpk_lo(u.w), d1.z, a2);
        a3 = fmaf(unpk_hi(u.w), d1.w, a3);
    }
    return (a0 + a1) + (a2 + a3);
}

// Register-array weights, EXACT round-0 form (proven: 57-dword array promoted,
// zero spill at 84 VGPRs with this float2-input loop). Do not change.
template<int NW>
__device__ __forceinline__ float dot_reg2(const unsigned (&w)[57],
                                          const float* __restrict__ in, float acc) {
    const float2* in2 = (const float2*)in;
    float a0 = acc, a1 = 0.f;
    #pragma unroll
    for (int i = 0; i < NW; ++i) {
        unsigned u = w[i];
        float2 d = in2[i];
        a0 = fmaf(unpk_lo(u), d.x, a0);
        a1 = fmaf(unpk_hi(u), d.y, a1);
    }
    return a0 + a1;
}

// W[O][K] row-major -> dst[o*S + kp] packed bf16 pairs (Kw = K/2 dwords used,
// S = row stride in dwords, multiple of 4; pads pre-zeroed by caller)
__device__ void load_rows(unsigned* dst, const void* src, int O, int Kw, int K, int S,
                          int tid, int nt, bool f32) {
    for (int i = tid; i < O * Kw; i += nt) {
        int o = i / Kw, kp = i - o * Kw;
        dst[o * S + kp] = pack2(gld(src, o * K + 2 * kp, f32),
                                gld(src, o * K + 2 * kp + 1, f32));
    }
}

__global__ __launch_bounds__(NTHREADS, 1)
void rnn_fused(const void* __restrict__ x,
               const void* __restrict__ dense_w, const void* __restrict__ dense_b,
               const void* __restrict__ vad_w_ih, const void* __restrict__ vad_w_hh,
               const void* __restrict__ vad_b_ih, const void* __restrict__ vad_b_hh,
               const void* __restrict__ vad_out_w, const void* __restrict__ vad_out_b,
               const void* __restrict__ noise_w_ih, const void* __restrict__ noise_w_hh,
               const void* __restrict__ noise_b_ih, const void* __restrict__ noise_b_hh,
               const void* __restrict__ den_w_ih, const void* __restrict__ den_w_hh,
               const void* __restrict__ den_b_ih, const void* __restrict__ den_b_hh,
               const void* __restrict__ out_w, const void* __restrict__ out_b,
               void* __restrict__ d_out) {
    // ---- LDS weights (packed bf16, uint4-readable, strides 12/28/52 dw) ----
    __shared__ __align__(16) unsigned sDW[24 * 28];    // dense rows (21dw used)
    __shared__ __align__(16) unsigned sVIH[72 * 12];   // vad ih rows (12dw)
    __shared__ __align__(16) unsigned sVHH[72 * 12];   // vad hh rows (12dw)
    __shared__ __align__(16) unsigned sNIH[144 * 52];  // noise ih rows (45dw used)
    __shared__ __align__(16) unsigned sNHH[144 * 28];  // noise hh rows (24dw used)
    __shared__ __align__(16) unsigned sOW[22 * 52];    // out rows (48dw used)
    __shared__ __align__(16) unsigned sVOW[12];        // vad_out row
    // ---- LDS activations/state/partials (fp32) ----
    __shared__ __align__(16) float sXT[48];    // x(t) (+6 pad zeros)
    __shared__ __align__(16) float sTMP[24];   // dense out
    __shared__ __align__(16) float sHV[24];    // h_vad
    __shared__ __align__(16) float sHN[48];    // h_noise
    __shared__ __align__(16) float sHD[96];    // h_den
    __shared__ __align__(16) float sHR[96];    // relu(h_den)
    __shared__ __align__(16) float sNIN[96];   // [tmp | vad | x] (+6 pad)
    __shared__ __align__(16) float sDIN[116];  // [vad | relu(noise) | x] (+2 pad)
    __shared__ float sNPI[144], sNPH[144];     // noise partials
    __shared__ float sGI[288], sGH[288];       // den partials
    __shared__ int sBad;

    const int tid = threadIdx.x;
    const int b = blockIdx.x;
    const int nt = NTHREADS;

    // ---- zero weight LDS (pads must be 0), init sBad ----
    if (tid == 0) sBad = 0;
    for (int i = tid; i < 24 * 28; i += nt) sDW[i] = 0u;
    for (int i = tid; i < 72 * 12; i += nt) { sVIH[i] = 0u; sVHH[i] = 0u; }
    for (int i = tid; i < 144 * 52; i += nt) sNIH[i] = 0u;
    for (int i = tid; i < 144 * 28; i += nt) sNHH[i] = 0u;
    for (int i = tid; i < 22 * 52; i += nt) sOW[i] = 0u;
    if (tid < 12) sVOW[tid] = 0u;
    __syncthreads();

    // ---- dtype detection (validated rounds 0-5) ----
    {
        const unsigned* w = (const unsigned*)dense_w;
        for (int i = tid; i < 500; i += nt) {
            float av = fabsf(unpk_lo(w[i]));
            if (!(av <= 1e3f)) { atomicAdd(&sBad, 1); break; }
        }
    }
    __syncthreads();
    const bool F32 = (sBad > 0);

    const float* xbf = (const float*)x + (size_t)b * TT * FF;
    const __hip_bfloat16* xbh = (const __hip_bfloat16*)x + (size_t)b * TT * FF;
    float* odf = (float*)d_out;
    __hip_bfloat16* odh = (__hip_bfloat16*)d_out;
    float* ovf = odf + (size_t)BB * TT * 22;
    __hip_bfloat16* ovh = odh + (size_t)BB * TT * 22;

    // ---- fill LDS weights ----
    load_rows(sDW,  dense_w,    24, 21, 42, 28, tid, nt, F32);
    load_rows(sVIH, vad_w_ih,   72, 12, 24, 12, tid, nt, F32);
    load_rows(sVHH, vad_w_hh,   72, 12, 24, 12, tid, nt, F32);
    load_rows(sNIH, noise_w_ih, 144, 45, 90, 52, tid, nt, F32);
    load_rows(sNHH, noise_w_hh, 144, 24, 48, 28, tid, nt, F32);
    load_rows(sOW,  out_w,      22, 48, 96, 52, tid, nt, F32);
    if (tid < 12) sVOW[tid] = pack2(gld(vad_out_w, 2 * tid, F32),
                                    gld(vad_out_w, 2 * tid + 1, F32));

    // ---- den weights in registers: EXACT round-0 form (proven promoted).
    //      ih rows on tid 0..287 (57 dw), hh rows on tid 320..607 (48 dw).
    //      These threads run ONLY dot_reg2 dots + tiny updates. ----
    unsigned wden[57];
    float bDen = 0.f;
    if (tid < 288) {
        #pragma unroll
        for (int i = 0; i < 57; ++i)
            wden[i] = pack2(gld(den_w_ih, tid * 114 + 2 * i, F32),
                            gld(den_w_ih, tid * 114 + 2 * i + 1, F32));
        bDen = gld(den_b_ih, tid, F32);
    } else if (tid >= 320 && tid < 608) {
        int o = tid - 320;
        #pragma unroll
        for (int i = 0; i < 48; ++i)
            wden[i] = pack2(gld(den_w_hh, o * 96 + 2 * i, F32),
                            gld(den_w_hh, o * 96 + 2 * i + 1, F32));
        #pragma unroll
        for (int i = 48; i < 57; ++i) wden[i] = 0u;
        bDen = gld(den_b_hh, o, F32);
    } else {
        #pragma unroll
        for (int i = 0; i < 57; ++i) wden[i] = 0u;
    }

    // ---- per-role bias scalars (array-free roles live on tids >= 608) ----
    float bDn = 0.f, bNI = 0.f, bNH = 0.f, bOut = 0.f, bVo = 0.f;
    float bv0 = 0.f, bv1 = 0.f, bv2 = 0.f, bv3 = 0.f, bv4 = 0.f, bv5 = 0.f;
    float hvreg = 0.f;
    if (tid >= 864 && tid < 888) bDn = gld(dense_b, tid - 864, F32);
    if (tid >= 288 && tid < 312) {
        int o = tid - 288;
        bv0 = gld(vad_b_ih, o, F32);      bv1 = gld(vad_b_ih, 24 + o, F32);
        bv2 = gld(vad_b_ih, 48 + o, F32); bv3 = gld(vad_b_hh, o, F32);
        bv4 = gld(vad_b_hh, 24 + o, F32); bv5 = gld(vad_b_hh, 48 + o, F32);
    }
    if (tid == 312) bVo = gld(vad_out_b, 0, F32);
    if (tid >= 608 && tid < 752) bNI = gld(noise_b_ih, tid - 608, F32);
    if (tid >= 752 && tid < 896) bNH = gld(noise_b_hh, tid - 752, F32);
    if (tid >= 608 && tid < 630) bOut = gld(out_b, tid - 608, F32);

    // ---- prologue: zero state, stage x(0), prefetch x(1) ----
    for (int i = tid; i < 24; i += nt) { sHV[i] = 0.f; sTMP[i] = 0.f; }
    for (int i = tid; i < 48; i += nt) sHN[i] = 0.f;
    for (int i = tid; i < 96; i += nt) { sHD[i] = 0.f; sHR[i] = 0.f; }
    if (tid < 6) { sXT[42 + tid] = 0.f; sNIN[90 + tid] = 0.f; }
    if (tid < 2) sDIN[114 + tid] = 0.f;
    if (tid < FF) {
        float v = F32 ? xbf[tid] : bf2f(xbh[tid]);
        sXT[tid] = v; sNIN[48 + tid] = v; sDIN[72 + tid] = v;
    }
    float xreg = 0.f;
    if (tid >= 752 && tid < 752 + FF) {
        int j = tid - 752;
        xreg = F32 ? xbf[FF + j] : bf2f(xbh[FF + j]);
    }
    __syncthreads();
    // dense(0) on array-free threads
    if (tid >= 864 && tid < 888) {
        int o = tid - 864;
        float v = tanh_fast(dotL<6>(sDW + o * 28, (const float4*)sXT, bDn));
        sTMP[o] = v; sNIN[o] = v;
    }
    __syncthreads();

    for (int t = 0; t < TT; ++t) {
        // ---- S2: den hh [320-607, regs/float2] || vad GRU [288-311, LDS]
        //          || out head(t-1) [608-629, LDS] ----
        if (tid >= 320 && tid < 608) {
            sGH[tid - 320] = dot_reg2<48>(wden, sHD, bDen);
        } else if (tid >= 288 && tid < 312) {
            // all 24 vad threads in one wave: lockstep read-then-write of sHV ok
            int o = tid - 288;
            const float4* tmp4 = (const float4*)sTMP;
            const float4* hv4 = (const float4*)sHV;
            const unsigned* wi = sVIH + o * 12;
            const unsigned* wh = sVHH + o * 12;
            float xr = dotL<3>(wi,       tmp4, bv0);
            float xz = dotL<3>(wi + 288, tmp4, bv1);
            float xn = dotL<3>(wi + 576, tmp4, bv2);
            float hr = dotL<3>(wh,       hv4, bv3);
            float hz = dotL<3>(wh + 288, hv4, bv4);
            float hn = dotL<3>(wh + 576, hv4, bv5);
            float r = sig(xr + hr);
            float z = sig(xz + hz);
            float n = tanh_fast(xn + r * hn);
            float h = (1.f - z) * n + z * hvreg;
            hvreg = h;
            sHV[o] = h; sNIN[24 + o] = h; sDIN[o] = h;
        } else if (tid >= 608 && tid < 630) {
            if (t > 0) {
                int o = tid - 608;
                float v = sig(dotL<12>(sOW + o * 52, (const float4*)sHR, bOut));
                size_t oi = ((size_t)b * TT + (t - 1)) * 22 + o;
                if (F32) odf[oi] = v; else odh[oi] = __float2bfloat16(v);
            }
        }
        __syncthreads();

        // ---- S3: noise ih [608-751] || noise hh [752-895] || vad_out [312] ----
        if (tid >= 608 && tid < 752) {
            sNPI[tid - 608] = dotL<12>(sNIH + (tid - 608) * 52, (const float4*)sNIN, bNI);
        } else if (tid >= 752) {
            sNPH[tid - 752] = dotL<6>(sNHH + (tid - 752) * 28, (const float4*)sHN, bNH);
        } else if (tid == 312) {
            float v = sig(dotL<3>(sVOW, (const float4*)sHV, bVo));
            size_t oi = (size_t)b * TT + t;
            if (F32) ovf[oi] = v; else ovh[oi] = __float2bfloat16(v);
        }
        __syncthreads();

        // ---- S4: noise update [0-47] ----
        if (tid < 48) {
            float r = sig(sNPI[tid] + sNPH[tid]);
            float z = sig(sNPI[48 + tid] + sNPH[48 + tid]);
            float n = tanh_fast(sNPI[96 + tid] + r * sNPH[96 + tid]);
            float h = (1.f - z) * n + z * sHN[tid];
            sHN[tid] = h;
            sDIN[24 + tid] = fmaxf(h, 0.f);
        }
        __syncthreads();

        // ---- S5: den ih [0-287, regs/float2] || x(t+1)->sXT,sNIN [752-793] ----
        if (tid < 288) {
            sGI[tid] = dot_reg2<57>(wden, sDIN, bDen);
        } else if (tid >= 752 && tid < 752 + FF) {
            int j = tid - 752;
            sXT[j] = xreg; sNIN[48 + j] = xreg;
            int t2 = (t + 2 < TT) ? (t + 2) : (TT - 1);
            xreg = F32 ? xbf[t2 * FF + j] : bf2f(xbh[t2 * FF + j]);
        }
        __syncthreads();

        // ---- S6: den update [0-95] || dense(t+1) [864-887, LDS]
        //          || x->sDIN [640-681] ----
        if (tid < 96) {
            float r = sig(sGI[tid] + sGH[tid]);
            float z = sig(sGI[96 + tid] + sGH[96 + tid]);
            float n = tanh_fast(sGI[192 + tid] + r * sGH[192 + tid]);
            float h = (1.f - z) * n + z * sHD[tid];
            sHD[tid] = h;
            sHR[tid] = fmaxf(h, 0.f);
        } else if (tid >= 864 && tid < 888) {
            int o = tid - 864;
            float v = tanh_fast(dotL<6>(sDW + o * 28, (const float4*)sXT, bDn));
            sTMP[o] = v; sNIN[o] = v;
        } else if (tid >= 640 && tid < 640 + FF) {
            int j = tid - 640;
            sDIN[72 + j] = sXT[j];
        }
        __syncthreads();
    }

    // ---- epilogue: out head for t = TT-1 ----
    if (tid >= 608 && tid < 630) {
        int o = tid - 608;
        float v = sig(dotL<12>(sOW + o * 52, (const float4*)sHR, bOut));
        size_t oi = ((size_t)b * TT + (TT - 1)) * 22 + o;
        if (F32) odf[oi] = v; else odh[oi] = __float2bfloat16(v);
    }
}

extern "C" void kernel_launch(void* const* d_in, const int* in_sizes, int n_in,
                              void* d_out, int out_size, void* d_ws, size_t ws_size,
                              hipStream_t stream) {
    hipLaunchKernelGGL(rnn_fused, dim3(BB), dim3(NTHREADS), 0, stream,
                       d_in[0], d_in[1], d_in[2],
                       d_in[3], d_in[4], d_in[5], d_in[6],
                       d_in[7], d_in[8],
                       d_in[9], d_in[10], d_in[11], d_in[12],
                       d_in[13], d_in[14], d_in[15], d_in[16],
                       d_in[17], d_in[18], d_out);
}

// Round 7
// 13106.421 us; speedup vs baseline: 3.0045x; 3.0045x over previous
//
#include <hip/hip_runtime.h>
#include <hip/hip_bf16.h>

#define BB 256
#define TT 2000
#define FF 42
#define NTHREADS 640

__device__ __forceinline__ float bf2f(__hip_bfloat16 v) { return __bfloat162float(v); }
__device__ __forceinline__ float sig(float x) { return 1.0f / (1.0f + __expf(-x)); }
__device__ __forceinline__ float tanh_fast(float x) {
    float e = __expf(2.0f * x);
    return 1.0f - 2.0f / (e + 1.0f);
}
__device__ __forceinline__ float unpk_lo(unsigned u) {
    union { unsigned u; float f; } c; c.u = u << 16; return c.f;
}
__device__ __forceinline__ float unpk_hi(unsigned u) {
    union { unsigned u; float f; } c; c.u = u & 0xffff0000u; return c.f;
}
// fp32 -> bf16 bits, round-to-nearest-even
__device__ __forceinline__ unsigned f2bfbits(float f) {
    union { float f; unsigned u; } c; c.f = f;
    unsigned r = c.u + 0x7FFFu + ((c.u >> 16) & 1u);
    return r >> 16;
}
__device__ __forceinline__ unsigned pack2(float a, float b) {
    return f2bfbits(a) | (f2bfbits(b) << 16);
}
__device__ __forceinline__ float gld(const void* p, int i, bool f32) {
    return f32 ? ((const float*)p)[i] : bf2f(((const __hip_bfloat16*)p)[i]);
}

// ============ PROVEN-FORM CONSTRAINTS (rounds 0-6 hardware A/B) ============
// * 640 threads -> allocator pins 84 VGPRs. Do not change block size.
// * wden[57] register array + dot_reg2 (b32 regs, float2 LDS input): proven
//   promoted & spill-free at 84 VGPRs (round 0). Do not change its form.
// * dot_w2 (b32 LDS weights, float2 LDS input): proven spill-free on ALL
//   roles incl. wden-holders (round 0).
// * uint4/float4 dotL on ANY thread of this kernel: proven to spill
//   (rounds 5/6). Do not reintroduce.
// ===========================================================================

// packed bf16 LDS weight row · fp32 input (LDS float2 reads), 2 acc chains
template<int NW>
__device__ __forceinline__ float dot_w2(const unsigned* __restrict__ w,
                                        const float* __restrict__ in, float acc) {
    const float2* in2 = (const float2*)in;
    float a0 = acc, a1 = 0.f;
    #pragma unroll
    for (int i = 0; i < NW; ++i) {
        unsigned u = w[i];
        float2 d = in2[i];
        a0 = fmaf(unpk_lo(u), d.x, a0);
        a1 = fmaf(unpk_hi(u), d.y, a1);
    }
    return a0 + a1;
}
// packed bf16 weight row (registers) · fp32 input (LDS float2)
template<int NW>
__device__ __forceinline__ float dot_reg2(const unsigned (&w)[57],
                                          const float* __restrict__ in, float acc) {
    const float2* in2 = (const float2*)in;
    float a0 = acc, a1 = 0.f;
    #pragma unroll
    for (int i = 0; i < NW; ++i) {
        unsigned u = w[i];
        float2 d = in2[i];
        a0 = fmaf(unpk_lo(u), d.x, a0);
        a1 = fmaf(unpk_hi(u), d.y, a1);
    }
    return a0 + a1;
}

// W[O][K] row-major -> dst[o*S + kp] packed bf16 pairs (Kw = K/2, S = stride)
__device__ void load_rows(unsigned* dst, const void* src, int O, int Kw, int K, int S,
                          int tid, int nt, bool f32) {
    for (int i = tid; i < O * Kw; i += nt) {
        int o = i / Kw, kp = i - o * Kw;
        dst[o * S + kp] = pack2(gld(src, o * K + 2 * kp, f32),
                                gld(src, o * K + 2 * kp + 1, f32));
    }
}

__global__ __launch_bounds__(NTHREADS, 1)
void rnn_fused(const void* __restrict__ x,
               const void* __restrict__ dense_w, const void* __restrict__ dense_b,
               const void* __restrict__ vad_w_ih, const void* __restrict__ vad_w_hh,
               const void* __restrict__ vad_b_ih, const void* __restrict__ vad_b_hh,
               const void* __restrict__ vad_out_w, const void* __restrict__ vad_out_b,
               const void* __restrict__ noise_w_ih, const void* __restrict__ noise_w_hh,
               const void* __restrict__ noise_b_ih, const void* __restrict__ noise_b_hh,
               const void* __restrict__ den_w_ih, const void* __restrict__ den_w_hh,
               const void* __restrict__ den_b_ih, const void* __restrict__ den_b_hh,
               const void* __restrict__ out_w, const void* __restrict__ out_b,
               void* __restrict__ d_out) {
    // ---- LDS: round-0 b32 weight layout (~54 KiB) + activations ----
    __shared__ __align__(16) unsigned sDWp[24 * 21];   // dense rows
    __shared__ __align__(16) unsigned sVIHp[72 * 13];  // vad ih rows (12w, stride 13)
    __shared__ __align__(16) unsigned sVHHp[72 * 13];
    __shared__ __align__(16) unsigned sNIHp[144 * 45]; // noise ih rows
    __shared__ __align__(16) unsigned sNHHp[144 * 25]; // noise hh rows (24w, stride 25)
    __shared__ __align__(16) unsigned sOWp[22 * 49];   // out rows (48w, stride 49)
    __shared__ unsigned sVOWp[12];
    __shared__ __align__(16) float sXT[44];    // x(t) fp32 (+pad)
    __shared__ __align__(16) float sTMP[24];   // dense out
    __shared__ __align__(16) float sHV[24];    // h_vad
    __shared__ __align__(16) float sHN[48];    // h_noise
    __shared__ __align__(16) float sHD[96];    // h_den
    __shared__ __align__(16) float sHR[96];    // relu(h_den)
    __shared__ __align__(16) float sNIN[92];   // [tmp | vad | x] (+pad)
    __shared__ __align__(16) float sDIN[116];  // [vad | relu(noise) | x] (+pad)
    __shared__ float sNPI[144], sNPH[144];     // noise partials
    __shared__ float sGI[288], sGH[288];       // den partials
    __shared__ int sBad;

    const int tid = threadIdx.x;
    const int b = blockIdx.x;
    const int nt = NTHREADS;

    // ---- dtype detection (validated rounds 0-6) ----
    if (tid == 0) sBad = 0;
    __syncthreads();
    {
        const unsigned* w = (const unsigned*)dense_w;
        for (int i = tid; i < 500; i += nt) {
            float av = fabsf(unpk_lo(w[i]));
            if (!(av <= 1e3f)) { atomicAdd(&sBad, 1); break; }
        }
    }
    __syncthreads();
    const bool F32 = (sBad > 0);

    const float* xbf = (const float*)x + (size_t)b * TT * FF;
    const __hip_bfloat16* xbh = (const __hip_bfloat16*)x + (size_t)b * TT * FF;
    float* odf = (float*)d_out;
    __hip_bfloat16* odh = (__hip_bfloat16*)d_out;
    float* ovf = odf + (size_t)BB * TT * 22;
    __hip_bfloat16* ovh = odh + (size_t)BB * TT * 22;

    // ---- fill LDS weights (round-0 layout) ----
    load_rows(sDWp,  dense_w,    24, 21, 42, 21, tid, nt, F32);
    load_rows(sVIHp, vad_w_ih,   72, 12, 24, 13, tid, nt, F32);
    load_rows(sVHHp, vad_w_hh,   72, 12, 24, 13, tid, nt, F32);
    load_rows(sNIHp, noise_w_ih, 144, 45, 90, 45, tid, nt, F32);
    load_rows(sNHHp, noise_w_hh, 144, 24, 48, 25, tid, nt, F32);
    load_rows(sOWp,  out_w,      22, 48, 96, 49, tid, nt, F32);
    if (tid < 12) sVOWp[tid] = pack2(gld(vad_out_w, 2 * tid, F32),
                                     gld(vad_out_w, 2 * tid + 1, F32));

    // ---- den weights in registers: EXACT round-0 form (proven promoted) ----
    unsigned wden[57];
    float bDen = 0.f;
    if (tid < 288) {
        #pragma unroll
        for (int i = 0; i < 57; ++i)
            wden[i] = pack2(gld(den_w_ih, tid * 114 + 2 * i, F32),
                            gld(den_w_ih, tid * 114 + 2 * i + 1, F32));
        bDen = gld(den_b_ih, tid, F32);
    } else if (tid >= 320 && tid < 608) {
        int o = tid - 320;
        #pragma unroll
        for (int i = 0; i < 48; ++i)
            wden[i] = pack2(gld(den_w_hh, o * 96 + 2 * i, F32),
                            gld(den_w_hh, o * 96 + 2 * i + 1, F32));
        #pragma unroll
        for (int i = 48; i < 57; ++i) wden[i] = 0u;
        bDen = gld(den_b_hh, o, F32);
    } else {
        #pragma unroll
        for (int i = 0; i < 57; ++i) wden[i] = 0u;
    }

    // ---- per-role bias scalars ----
    float bDn = 0.f, bNI = 0.f, bNH = 0.f, bOut = 0.f, bVo = 0.f;
    float bv0 = 0.f, bv1 = 0.f, bv2 = 0.f, bv3 = 0.f, bv4 = 0.f, bv5 = 0.f;
    float hvreg = 0.f;
    if (tid >= 96 && tid < 120) bDn = gld(dense_b, tid - 96, F32);
    if (tid >= 288 && tid < 312) {
        int o = tid - 288;
        bv0 = gld(vad_b_ih, o, F32);      bv1 = gld(vad_b_ih, 24 + o, F32);
        bv2 = gld(vad_b_ih, 48 + o, F32); bv3 = gld(vad_b_hh, o, F32);
        bv4 = gld(vad_b_hh, 24 + o, F32); bv5 = gld(vad_b_hh, 48 + o, F32);
    }
    if (tid == 312) bVo = gld(vad_out_b, 0, F32);
    if (tid >= 320 && tid < 464) bNI = gld(noise_b_ih, tid - 320, F32);
    if (tid >= 464 && tid < 608) bNH = gld(noise_b_hh, tid - 464, F32);
    if (tid >= 608 && tid < 630) bOut = gld(out_b, tid - 608, F32);

    // ---- prologue: zero state, stage x(0), prefetch x(1) ----
    for (int i = tid; i < 24; i += nt) { sHV[i] = 0.f; sTMP[i] = 0.f; }
    for (int i = tid; i < 48; i += nt) sHN[i] = 0.f;
    for (int i = tid; i < 96; i += nt) { sHD[i] = 0.f; sHR[i] = 0.f; }
    if (tid < 2) { sXT[42 + tid] = 0.f; sNIN[90 + tid] = 0.f; sDIN[114 + tid] = 0.f; }
    if (tid < FF) {
        float v = F32 ? xbf[tid] : bf2f(xbh[tid]);
        sXT[tid] = v; sNIN[48 + tid] = v; sDIN[72 + tid] = v;
    }
    float xreg = 0.f;
    if (tid >= 464 && tid < 464 + FF) {
        int j = tid - 464;
        xreg = F32 ? xbf[FF + j] : bf2f(xbh[FF + j]);
    }
    __syncthreads();
    // dense(0)
    if (tid >= 96 && tid < 120) {
        int o = tid - 96;
        float v = tanh_fast(dot_w2<21>(sDWp + o * 21, sXT, bDn));
        sTMP[o] = v; sNIN[o] = v;
    }
    __syncthreads();

    for (int t = 0; t < TT; ++t) {
        // ---- S2: den hh [320-607, regs] || vad fused GRU [288-311, LDS b32]
        //          || out head(t-1) [608-629, LDS b32] ----
        if (tid >= 320 && tid < 608) {
            sGH[tid - 320] = dot_reg2<48>(wden, sHD, bDen);
        } else if (tid >= 288 && tid < 312) {
            // all 24 vad threads in wave 4: lockstep read-then-write of sHV ok
            int o = tid - 288;
            const unsigned* wi = sVIHp + o * 13;
            const unsigned* wh = sVHHp + o * 13;
            float xr = dot_w2<12>(wi,       sTMP, bv0);
            float xz = dot_w2<12>(wi + 312, sTMP, bv1);
            float xn = dot_w2<12>(wi + 624, sTMP, bv2);
            float hr = dot_w2<12>(wh,       sHV, bv3);
            float hz = dot_w2<12>(wh + 312, sHV, bv4);
            float hn = dot_w2<12>(wh + 624, sHV, bv5);
            float r = sig(xr + hr);
            float z = sig(xz + hz);
            float n = tanh_fast(xn + r * hn);
            float h = (1.f - z) * n + z * hvreg;
            hvreg = h;
            sHV[o] = h; sNIN[24 + o] = h; sDIN[o] = h;
        } else if (tid >= 608 && tid < 630) {
            if (t > 0) {
                int o = tid - 608;
                float v = sig(dot_w2<48>(sOWp + o * 49, sHR, bOut));
                size_t oi = ((size_t)b * TT + (t - 1)) * 22 + o;
                if (F32) odf[oi] = v; else odh[oi] = __float2bfloat16(v);
            }
        }
        __syncthreads();

        // ---- S3: noise ih [320-463] || noise hh [464-607] || vad_out [312] ----
        if (tid >= 320 && tid < 464) {
            sNPI[tid - 320] = dot_w2<45>(sNIHp + (tid - 320) * 45, sNIN, bNI);
        } else if (tid >= 464 && tid < 608) {
            sNPH[tid - 464] = dot_w2<24>(sNHHp + (tid - 464) * 25, sHN, bNH);
        } else if (tid == 312) {
            float v = sig(dot_w2<12>(sVOWp, sHV, bVo));
            size_t oi = (size_t)b * TT + t;
            if (F32) ovf[oi] = v; else ovh[oi] = __float2bfloat16(v);
        }
        __syncthreads();

        // ---- S4: noise update [0-47] ----
        if (tid < 48) {
            float r = sig(sNPI[tid] + sNPH[tid]);
            float z = sig(sNPI[48 + tid] + sNPH[48 + tid]);
            float n = tanh_fast(sNPI[96 + tid] + r * sNPH[96 + tid]);
            float h = (1.f - z) * n + z * sHN[tid];
            sHN[tid] = h;
            sDIN[24 + tid] = fmaxf(h, 0.f);
        }
        __syncthreads();

        // ---- S5: den ih [0-287, regs] || x(t+1)->sXT,sNIN [464-505] ----
        if (tid < 288) {
            sGI[tid] = dot_reg2<57>(wden, sDIN, bDen);
        } else if (tid >= 464 && tid < 464 + FF) {
            int j = tid - 464;
            sXT[j] = xreg; sNIN[48 + j] = xreg;
            int t2 = (t + 2 < TT) ? (t + 2) : (TT - 1);
            xreg = F32 ? xbf[t2 * FF + j] : bf2f(xbh[t2 * FF + j]);
        }
        __syncthreads();

        // ---- S6: den update [0-95] || dense(t+1) [96-119] || x->sDIN [128-169] ----
        if (tid < 96) {
            float r = sig(sGI[tid] + sGH[tid]);
            float z = sig(sGI[96 + tid] + sGH[96 + tid]);
            float n = tanh_fast(sGI[192 + tid] + r * sGH[192 + tid]);
            float h = (1.f - z) * n + z * sHD[tid];
            sHD[tid] = h;
            sHR[tid] = fmaxf(h, 0.f);
        } else if (tid < 120) {
            int o = tid - 96;
            float v = tanh_fast(dot_w2<21>(sDWp + o * 21, sXT, bDn));
            sTMP[o] = v; sNIN[o] = v;
        } else if (tid >= 128 && tid < 128 + FF) {
            int j = tid - 128;
            sDIN[72 + j] = sXT[j];
        }
        __syncthreads();
    }

    // ---- epilogue: out head for t = TT-1 ----
    if (tid >= 608 && tid < 630) {
        int o = tid - 608;
        float v = sig(dot_w2<48>(sOWp + o * 49, sHR, bOut));
        size_t oi = ((size_t)b * TT + (TT - 1)) * 22 + o;
        if (F32) odf[oi] = v; else odh[oi] = __float2bfloat16(v);
    }
}

extern "C" void kernel_launch(void* const* d_in, const int* in_sizes, int n_in,
                              void* d_out, int out_size, void* d_ws, size_t ws_size,
                              hipStream_t stream) {
    hipLaunchKernelGGL(rnn_fused, dim3(BB), dim3(NTHREADS), 0, stream,
                       d_in[0], d_in[1], d_in[2],
                       d_in[3], d_in[4], d_in[5], d_in[6],
                       d_in[7], d_in[8],
                       d_in[9], d_in[10], d_in[11], d_in[12],
                       d_in[13], d_in[14], d_in[15], d_in[16],
                       d_in[17], d_in[18], d_out);
}

// Round 8
// 10556.474 us; speedup vs baseline: 3.7303x; 1.2416x over previous
//
#include <hip/hip_runtime.h>
#include <hip/hip_bf16.h>

#define BB 256
#define TT 2000
#define FF 42
#define NTHREADS 640

__device__ __forceinline__ float bf2f(__hip_bfloat16 v) { return __bfloat162float(v); }
__device__ __forceinline__ float sig(float x) { return 1.0f / (1.0f + __expf(-x)); }
__device__ __forceinline__ float tanh_fast(float x) {
    float e = __expf(2.0f * x);
    return 1.0f - 2.0f / (e + 1.0f);
}
__device__ __forceinline__ float unpk_lo(unsigned u) {
    union { unsigned u; float f; } c; c.u = u << 16; return c.f;
}
__device__ __forceinline__ float unpk_hi(unsigned u) {
    union { unsigned u; float f; } c; c.u = u & 0xffff0000u; return c.f;
}
// fp32 -> bf16 bits, round-to-nearest-even
__device__ __forceinline__ unsigned f2bfbits(float f) {
    union { float f; unsigned u; } c; c.f = f;
    unsigned r = c.u + 0x7FFFu + ((c.u >> 16) & 1u);
    return r >> 16;
}
__device__ __forceinline__ unsigned pack2(float a, float b) {
    return f2bfbits(a) | (f2bfbits(b) << 16);
}
__device__ __forceinline__ float gld(const void* p, int i, bool f32) {
    return f32 ? ((const float*)p)[i] : bf2f(((const __hip_bfloat16*)p)[i]);
}

// ============ PROVEN-FORM CONSTRAINTS (rounds 0-7 hardware A/B) ============
// * 640 threads -> allocator pins 84 VGPRs. Do not change block size.
// * wden[57] register array + dot_reg2: proven promoted & spill-free (r0, r7).
// * dot_w2 (b32 LDS weights, float2 LDS input): proven spill-free on ALL
//   roles including wden-holders (round 0).
// * uint4/float4 dots anywhere in this kernel: proven to spill (r5/r6).
// This round changes ONLY the schedule: 3-stage layer-pipelined (den lags
// 3 steps, noise 2, vad 1 behind dense), 3 barriers/step instead of 7.
// ===========================================================================

// packed bf16 LDS weight row · fp32 input (LDS float2 reads), 2 acc chains
template<int NW>
__device__ __forceinline__ float dot_w2(const unsigned* __restrict__ w,
                                        const float* __restrict__ in, float acc) {
    const float2* in2 = (const float2*)in;
    float a0 = acc, a1 = 0.f;
    #pragma unroll
    for (int i = 0; i < NW; ++i) {
        unsigned u = w[i];
        float2 d = in2[i];
        a0 = fmaf(unpk_lo(u), d.x, a0);
        a1 = fmaf(unpk_hi(u), d.y, a1);
    }
    return a0 + a1;
}
// packed bf16 weight row (registers) · fp32 input (LDS float2)
template<int NW>
__device__ __forceinline__ float dot_reg2(const unsigned (&w)[57],
                                          const float* __restrict__ in, float acc) {
    const float2* in2 = (const float2*)in;
    float a0 = acc, a1 = 0.f;
    #pragma unroll
    for (int i = 0; i < NW; ++i) {
        unsigned u = w[i];
        float2 d = in2[i];
        a0 = fmaf(unpk_lo(u), d.x, a0);
        a1 = fmaf(unpk_hi(u), d.y, a1);
    }
    return a0 + a1;
}

// W[O][K] row-major -> dst[o*S + kp] packed bf16 pairs (Kw = K/2, S = stride)
__device__ void load_rows(unsigned* dst, const void* src, int O, int Kw, int K, int S,
                          int tid, int nt, bool f32) {
    for (int i = tid; i < O * Kw; i += nt) {
        int o = i / Kw, kp = i - o * Kw;
        dst[o * S + kp] = pack2(gld(src, o * K + 2 * kp, f32),
                                gld(src, o * K + 2 * kp + 1, f32));
    }
}

__global__ __launch_bounds__(NTHREADS, 1)
void rnn_fused(const void* __restrict__ x,
               const void* __restrict__ dense_w, const void* __restrict__ dense_b,
               const void* __restrict__ vad_w_ih, const void* __restrict__ vad_w_hh,
               const void* __restrict__ vad_b_ih, const void* __restrict__ vad_b_hh,
               const void* __restrict__ vad_out_w, const void* __restrict__ vad_out_b,
               const void* __restrict__ noise_w_ih, const void* __restrict__ noise_w_hh,
               const void* __restrict__ noise_b_ih, const void* __restrict__ noise_b_hh,
               const void* __restrict__ den_w_ih, const void* __restrict__ den_w_hh,
               const void* __restrict__ den_b_ih, const void* __restrict__ den_b_hh,
               const void* __restrict__ out_w, const void* __restrict__ out_b,
               void* __restrict__ d_out) {
    // ---- LDS: round-0 b32 weight layout (odd strides => conflict-free) ----
    __shared__ __align__(16) unsigned sDWp[24 * 21];
    __shared__ __align__(16) unsigned sVIHp[72 * 13];
    __shared__ __align__(16) unsigned sVHHp[72 * 13];
    __shared__ __align__(16) unsigned sNIHp[144 * 45];
    __shared__ __align__(16) unsigned sNHHp[144 * 25];
    __shared__ __align__(16) unsigned sOWp[22 * 49];
    __shared__ unsigned sVOWp[12];
    __shared__ __align__(16) float sXT[44];        // x(k), written B, read C
    __shared__ __align__(16) float sTMP[24];       // tmp(k), written C, read next B
    __shared__ __align__(16) float sHV[24];        // h_vad
    __shared__ __align__(16) float sHN[48];        // h_noise
    __shared__ __align__(16) float sHD[96];        // h_den
    __shared__ __align__(16) float sHR[96];        // relu(h_den)
    __shared__ __align__(16) float sNIN[2][92];    // [tmp|hvad|x] parity t&1
    __shared__ __align__(16) float sDIN[2][116];   // [hvad|relu|x] parity t&1
    __shared__ float sVPI[72], sVPH[72];
    __shared__ float sNPI[144], sNPH[144];
    __shared__ float sGI[288], sGH[288];
    __shared__ int sBad;

    const int tid = threadIdx.x;
    const int b = blockIdx.x;
    const int nt = NTHREADS;

    // ---- dtype detection (validated rounds 0-7) ----
    if (tid == 0) sBad = 0;
    __syncthreads();
    {
        const unsigned* w = (const unsigned*)dense_w;
        for (int i = tid; i < 500; i += nt) {
            float av = fabsf(unpk_lo(w[i]));
            if (!(av <= 1e3f)) { atomicAdd(&sBad, 1); break; }
        }
    }
    __syncthreads();
    const bool F32 = (sBad > 0);

    const float* xbf = (const float*)x + (size_t)b * TT * FF;
    const __hip_bfloat16* xbh = (const __hip_bfloat16*)x + (size_t)b * TT * FF;
    float* odf = (float*)d_out;
    __hip_bfloat16* odh = (__hip_bfloat16*)d_out;
    float* ovf = odf + (size_t)BB * TT * 22;
    __hip_bfloat16* ovh = odh + (size_t)BB * TT * 22;

    // ---- fill LDS weights (round-0 layout) ----
    load_rows(sDWp,  dense_w,    24, 21, 42, 21, tid, nt, F32);
    load_rows(sVIHp, vad_w_ih,   72, 12, 24, 13, tid, nt, F32);
    load_rows(sVHHp, vad_w_hh,   72, 12, 24, 13, tid, nt, F32);
    load_rows(sNIHp, noise_w_ih, 144, 45, 90, 45, tid, nt, F32);
    load_rows(sNHHp, noise_w_hh, 144, 24, 48, 25, tid, nt, F32);
    load_rows(sOWp,  out_w,      22, 48, 96, 49, tid, nt, F32);
    if (tid < 12) sVOWp[tid] = pack2(gld(vad_out_w, 2 * tid, F32),
                                     gld(vad_out_w, 2 * tid + 1, F32));

    // ---- den weights in registers: EXACT round-0 form (proven promoted) ----
    unsigned wden[57];
    float bDen = 0.f;
    if (tid < 288) {
        #pragma unroll
        for (int i = 0; i < 57; ++i)
            wden[i] = pack2(gld(den_w_ih, tid * 114 + 2 * i, F32),
                            gld(den_w_ih, tid * 114 + 2 * i + 1, F32));
        bDen = gld(den_b_ih, tid, F32);
    } else if (tid >= 320 && tid < 608) {
        int o = tid - 320;
        #pragma unroll
        for (int i = 0; i < 48; ++i)
            wden[i] = pack2(gld(den_w_hh, o * 96 + 2 * i, F32),
                            gld(den_w_hh, o * 96 + 2 * i + 1, F32));
        #pragma unroll
        for (int i = 48; i < 57; ++i) wden[i] = 0u;
        bDen = gld(den_b_hh, o, F32);
    } else {
        #pragma unroll
        for (int i = 0; i < 57; ++i) wden[i] = 0u;
    }

    // ---- per-role bias scalars (new role map) ----
    float bVI = 0.f, bVH = 0.f, bNI = 0.f, bNH = 0.f;
    float bDn = 0.f, bOut = 0.f, bVo = 0.f;
    if (tid < 72) bVI = gld(vad_b_ih, tid, F32);
    if (tid >= 72 && tid < 144) bVH = gld(vad_b_hh, tid - 72, F32);
    if (tid >= 144 && tid < 288) bNI = gld(noise_b_ih, tid - 144, F32);
    if (tid >= 320 && tid < 464) bNH = gld(noise_b_hh, tid - 320, F32);
    if (tid >= 96 && tid < 120) bDn = gld(dense_b, tid - 96, F32);
    if (tid >= 608 && tid < 630) bOut = gld(out_b, tid - 608, F32);
    if (tid == 630) bVo = gld(vad_out_b, 0, F32);

    // ---- prologue: zero state + pads, stager register chain ----
    for (int i = tid; i < 24; i += nt) sHV[i] = 0.f;
    for (int i = tid; i < 48; i += nt) sHN[i] = 0.f;
    for (int i = tid; i < 96; i += nt) { sHD[i] = 0.f; sHR[i] = 0.f; }
    if (tid < 2) {
        sXT[42 + tid] = 0.f;
        sNIN[0][90 + tid] = 0.f; sNIN[1][90 + tid] = 0.f;
        sDIN[0][114 + tid] = 0.f; sDIN[1][114 + tid] = 0.f;
    }
    float xprev = 0.f, xs0 = 0.f, xs1 = 0.f, xs2 = 0.f;
    if (tid >= 560 && tid < 602) {
        int j = tid - 560;
        xs0 = F32 ? xbf[j] : bf2f(xbh[j]);
        xs1 = F32 ? xbf[FF + j] : bf2f(xbh[FF + j]);
    }
    __syncthreads();

    // ---- 3-stage layer-pipelined loop: at iter k compute
    //      den(k-3) partials | vad(k-1)/noise(k-2) partials + den(k-3) upd |
    //      vad/noise updates + dense(k). Heads lag: out(k-4), vad_out(k-2).
    for (int k = 0; k <= TT + 3; ++k) {
        const int pe = k & 1;        // parity of steps k, k-2
        const int po = pe ^ 1;       // parity of steps k-1, k-3

        // ======== Stage A ========
        if (tid < 288) {
            if (k >= 3 && k < TT + 3)
                sGI[tid] = dot_reg2<57>(wden, sDIN[po], bDen);
        } else if (tid >= 320 && tid < 608) {
            if (k >= 3 && k < TT + 3)
                sGH[tid - 320] = dot_reg2<48>(wden, sHD, bDen);
        } else if (tid >= 608 && tid < 630) {
            if (k >= 4) {
                int o = tid - 608;
                float v = sig(dot_w2<48>(sOWp + o * 49, sHR, bOut));
                size_t oi = ((size_t)b * TT + (k - 4)) * 22 + o;
                if (F32) odf[oi] = v; else odh[oi] = __float2bfloat16(v);
            }
        } else if (tid == 630) {
            if (k >= 2 && k < TT + 2) {
                float v = sig(dot_w2<12>(sVOWp, sHV, bVo));
                size_t oi = (size_t)b * TT + (k - 2);
                if (F32) ovf[oi] = v; else ovh[oi] = __float2bfloat16(v);
            }
        }
        __syncthreads();

        // ======== Stage B ========
        if (tid < 72) {
            if (k >= 1 && k < TT + 1)
                sVPI[tid] = dot_w2<12>(sVIHp + tid * 13, sTMP, bVI);
        } else if (tid < 144) {
            if (k >= 1 && k < TT + 1)
                sVPH[tid - 72] = dot_w2<12>(sVHHp + (tid - 72) * 13, sHV, bVH);
        } else if (tid < 288) {
            if (k >= 2 && k < TT + 2)
                sNPI[tid - 144] = dot_w2<45>(sNIHp + (tid - 144) * 45, sNIN[pe], bNI);
        } else if (tid >= 320 && tid < 464) {
            if (k >= 2 && k < TT + 2)
                sNPH[tid - 320] = dot_w2<24>(sNHHp + (tid - 320) * 25, sHN, bNH);
        } else if (tid >= 464 && tid < 560) {
            if (k >= 3 && k < TT + 3) {
                int o = tid - 464;
                float r = sig(sGI[o] + sGH[o]);
                float z = sig(sGI[96 + o] + sGH[96 + o]);
                float n = tanh_fast(sGI[192 + o] + r * sGH[192 + o]);
                float h = (1.f - z) * n + z * sHD[o];
                sHD[o] = h;
                sHR[o] = fmaxf(h, 0.f);
            }
        } else if (tid >= 560 && tid < 602) {
            int j = tid - 560;
            if (k < TT) sXT[j] = xs0;
            int t2 = (k + 2 < TT) ? (k + 2) : (TT - 1);
            xs2 = F32 ? xbf[t2 * FF + j] : bf2f(xbh[t2 * FF + j]);
        }
        __syncthreads();

        // ======== Stage C ========
        if (tid < 24) {
            if (k >= 1 && k < TT + 1) {
                int o = tid;
                float r = sig(sVPI[o] + sVPH[o]);
                float z = sig(sVPI[24 + o] + sVPH[24 + o]);
                float n = tanh_fast(sVPI[48 + o] + r * sVPH[48 + o]);
                float h = (1.f - z) * n + z * sHV[o];
                sHV[o] = h;
                sNIN[po][24 + o] = h;   // step k-1 buffer
                sDIN[po][o] = h;
            }
        } else if (tid < 72) {
            if (k >= 2 && k < TT + 2) {
                int o = tid - 24;
                float r = sig(sNPI[o] + sNPH[o]);
                float z = sig(sNPI[48 + o] + sNPH[48 + o]);
                float n = tanh_fast(sNPI[96 + o] + r * sNPH[96 + o]);
                float h = (1.f - z) * n + z * sHN[o];
                sHN[o] = h;
                sDIN[pe][24 + o] = fmaxf(h, 0.f);  // step k-2 buffer
            }
        } else if (tid >= 96 && tid < 120) {
            if (k < TT) {
                int o = tid - 96;
                float v = tanh_fast(dot_w2<21>(sDWp + o * 21, sXT, bDn));
                sTMP[o] = v;
                sNIN[pe][o] = v;        // step k buffer
            }
        } else if (tid >= 560 && tid < 602) {
            int j = tid - 560;
            if (k < TT) sNIN[pe][48 + j] = xs0;          // x(k)
            if (k >= 1 && k <= TT) sDIN[po][72 + j] = xprev;  // x(k-1)
            xprev = xs0; xs0 = xs1; xs1 = xs2;
        }
        __syncthreads();
    }
}

extern "C" void kernel_launch(void* const* d_in, const int* in_sizes, int n_in,
                              void* d_out, int out_size, void* d_ws, size_t ws_size,
                              hipStream_t stream) {
    hipLaunchKernelGGL(rnn_fused, dim3(BB), dim3(NTHREADS), 0, stream,
                       d_in[0], d_in[1], d_in[2],
                       d_in[3], d_in[4], d_in[5], d_in[6],
                       d_in[7], d_in[8],
                       d_in[9], d_in[10], d_in[11], d_in[12],
                       d_in[13], d_in[14], d_in[15], d_in[16],
                       d_in[17], d_in[18], d_out);
}